// Round 2
// baseline (692.554 us; speedup 1.0000x reference)
//
#include <hip/hip_runtime.h>
#include <hip/hip_bf16.h>

// GatherMatMul: out[b] = x[b] (1x4096) @ W[idx[b]] (4096x4096), fp32.
// B=16, N_EXPERTS=8, D=4096.
// Strategy: group samples by expert so each needed expert matrix is
// streamed from HBM exactly once (~7 distinct experts -> ~450 MB instead
// of 1 GiB). Memory-bound; target the HBM BW ceiling (~6.3 TB/s).

#define NEXP 8
#define BATCH 16
#define DIM 4096
#define SPB 8            // samples per block (compile-time -> acc stays in regs)
#define CHUNKS_PER_E 2   // ceil(BATCH / SPB)
#define COLS_PER_BLOCK 1024
#define COL_TILES (DIM / COLS_PER_BLOCK)   // 4
#define KCH 128
#define K_CHUNKS (DIM / KCH)               // 32

// --- Grouping kernel: bucket the 16 samples by expert id. ---
// Robust to indices arriving as int32 or int64: read the first 8 values as
// int64; genuine int64 indices are all in [0,8). If the memory is int32,
// each int64 read combines two values and lands >= 2^32 unless every
// odd-position value is 0 (negligible for random indices).
__global__ void group_kernel(const void* __restrict__ idx_raw,
                             int* __restrict__ counts,
                             int* __restrict__ lists) {
    if (threadIdx.x != 0 || blockIdx.x != 0) return;
    const long long* i64 = (const long long*)idx_raw;
    const int*       i32 = (const int*)idx_raw;
    bool is64 = true;
    for (int k = 0; k < 8; ++k) {           // 64 bytes, in-bounds either way
        long long v = i64[k];
        if (v < 0 || v >= NEXP) { is64 = false; break; }
    }
    int cnt[NEXP];
    for (int e = 0; e < NEXP; ++e) cnt[e] = 0;
    for (int b = 0; b < BATCH; ++b) {
        long long vi = is64 ? i64[b] : (long long)i32[b];
        int e = (int)(((vi % NEXP) + NEXP) % NEXP);
        lists[e * BATCH + cnt[e]] = b;
        cnt[e]++;
    }
    for (int e = 0; e < NEXP; ++e) counts[e] = cnt[e];
}

// --- Main kernel ---
// grid: (COL_TILES, K_CHUNKS, NEXP * CHUNKS_PER_E); block: 256 threads.
// Block (ct, kc, e*2+c): streams W[e][kc*128 .. +128)[ct*1024 .. +1024)
// exactly once (coalesced float4), applies it to up to 8 samples of
// expert e, atomically accumulates partial dots into out.
__global__ __launch_bounds__(256)
void gmm_kernel(const float* __restrict__ x,
                const float* __restrict__ W,
                const int* __restrict__ counts,
                const int* __restrict__ lists,
                float* __restrict__ out) {
    const int ez    = blockIdx.z;
    const int e     = ez >> 1;
    const int chunk = ez & 1;
    const int c_e   = counts[e];
    const int base_s = chunk * SPB;
    if (base_s >= c_e) return;                 // inactive expert-chunk
    const int nvalid = min(SPB, c_e - base_s);

    __shared__ float xs[SPB][KCH];
    __shared__ int   samp[SPB];

    const int tid   = threadIdx.x;
    const int krow0 = blockIdx.y * KCH;

    if (tid < SPB) {
        const int slot = base_s + tid;
        samp[tid] = (tid < nvalid) ? lists[e * BATCH + slot] : -1;
    }
    __syncthreads();

    // Stage x chunks: SPB*KCH = 1024 floats, 256 threads -> 4 each.
    for (int i = tid; i < SPB * KCH; i += 256) {
        const int s = i >> 7;        // i / KCH
        const int d = i & (KCH - 1); // i % KCH
        const int sm = samp[s];
        xs[s][d] = (sm >= 0) ? x[(size_t)sm * DIM + krow0 + d] : 0.0f;
    }
    __syncthreads();

    const int col0 = blockIdx.x * COLS_PER_BLOCK + tid * 4;
    const float4* Wp = (const float4*)(W + (size_t)e * DIM * DIM
                                        + (size_t)krow0 * DIM + col0);

    float4 acc[SPB];
#pragma unroll
    for (int s = 0; s < SPB; ++s) acc[s] = make_float4(0.f, 0.f, 0.f, 0.f);

#pragma unroll 4
    for (int d = 0; d < KCH; ++d) {
        const float4 w = Wp[(size_t)d * (DIM / 4)];
#pragma unroll
        for (int s = 0; s < SPB; ++s) {
            const float xv = xs[s][d];   // wave-uniform LDS broadcast
            acc[s].x = fmaf(xv, w.x, acc[s].x);
            acc[s].y = fmaf(xv, w.y, acc[s].y);
            acc[s].z = fmaf(xv, w.z, acc[s].z);
            acc[s].w = fmaf(xv, w.w, acc[s].w);
        }
    }

#pragma unroll
    for (int s = 0; s < SPB; ++s) {
        const int sm = samp[s];
        if (sm >= 0) {
            float* o = out + (size_t)sm * DIM + col0;
            atomicAdd(o + 0, acc[s].x);
            atomicAdd(o + 1, acc[s].y);
            atomicAdd(o + 2, acc[s].z);
            atomicAdd(o + 3, acc[s].w);
        }
    }
}

extern "C" void kernel_launch(void* const* d_in, const int* in_sizes, int n_in,
                              void* d_out, int out_size, void* d_ws, size_t ws_size,
                              hipStream_t stream) {
    const float* x   = (const float*)d_in[0];
    const void*  idx = d_in[1];
    const float* W   = (const float*)d_in[2];
    float* out = (float*)d_out;

    int* counts = (int*)d_ws;              // 8 ints
    int* lists  = counts + NEXP;           // 8*16 ints

    // d_out is poisoned 0xAA before every timed launch; we accumulate with
    // atomics, so zero it first (hipMemsetAsync is graph-capture-safe).
    hipMemsetAsync(d_out, 0, (size_t)out_size * sizeof(float), stream);

    group_kernel<<<1, 64, 0, stream>>>(idx, counts, lists);

    dim3 grid(COL_TILES, K_CHUNKS, NEXP * CHUNKS_PER_E);
    gmm_kernel<<<grid, 256, 0, stream>>>(x, W, counts, lists, out);
}

// Round 7
// 676.763 us; speedup vs baseline: 1.0233x; 1.0233x over previous
//
#include <hip/hip_runtime.h>

// GatherMatMul: out[b] = x[b] (1x4096) @ W[idx[b]] (4096x4096), fp32.
// B=16, N_EXPERTS=8, D=4096.
// Memory-bound: stream each DISTINCT expert matrix (~7 x 64 MiB ~ 450 MB)
// exactly once. Split-K across 32 chunks for block parallelism; fp32
// atomicAdd accumulation (device-scope, cross-XCD safe).
// R3 changes vs R2: fused per-block grouping (drops group_kernel dispatch),
// template<S> inner loop (kills 4x wasted FMAs at avg nvalid~2), d-major
// xs layout (wide LDS broadcast reads), unroll 8 (more loads in flight).

#define NEXP 8
#define BATCH 16
#define DIM 4096
#define SPB 8            // max samples per block-chunk (compile-time)
#define COLS_PER_BLOCK 1024
#define COL_TILES (DIM / COLS_PER_BLOCK)   // 4
#define KCH 128
#define K_CHUNKS (DIM / KCH)               // 32

template<int S>
__device__ __forceinline__ void inner_loop(const float4* __restrict__ Wp,
                                           const float (* __restrict__ xs)[SPB],
                                           float4* __restrict__ acc) {
#pragma unroll 8
    for (int d = 0; d < KCH; ++d) {
        const float4 w = Wp[(size_t)d * (DIM / 4)];
#pragma unroll
        for (int s = 0; s < S; ++s) {
            const float xv = xs[d][s];   // wave-uniform LDS broadcast
            acc[s].x = fmaf(xv, w.x, acc[s].x);
            acc[s].y = fmaf(xv, w.y, acc[s].y);
            acc[s].z = fmaf(xv, w.z, acc[s].z);
            acc[s].w = fmaf(xv, w.w, acc[s].w);
        }
    }
}

// grid: (COL_TILES, K_CHUNKS, NEXP * 2); block: 256 threads.
// Block (ct, kc, e*2+chunk): streams W[e][kc*128 .. +128)[ct*1024 .. +1024)
// once (coalesced float4), applies it to up to 8 samples of expert e.
__global__ __launch_bounds__(256)
void gmm_kernel(const float* __restrict__ x,
                const void* __restrict__ idx_raw,
                const float* __restrict__ W,
                float* __restrict__ out) {
    __shared__ int   s_samp[SPB];
    __shared__ int   s_nv;
    __shared__ float xs[KCH][SPB];   // d-major: per-d samples contiguous

    const int tid   = threadIdx.x;
    const int e     = blockIdx.z >> 1;
    const int chunk = blockIdx.z & 1;

    // Fused grouping: thread 0 buckets the 16 indices for THIS expert.
    // dtype sniff: read first 8 as int64; genuine int64 values are in
    // [0,8). int32 memory read as int64 pairs values and lands >= 2^32
    // unless every odd-position value is 0 (not the case for this seed).
    if (tid == 0) {
        const long long* i64 = (const long long*)idx_raw;
        const int*       i32 = (const int*)idx_raw;
        bool is64 = true;
        for (int k = 0; k < 8; ++k) {
            const long long v = i64[k];
            if (v < 0 || v >= NEXP) { is64 = false; break; }
        }
        const int base = chunk * SPB;
        int cnt = 0, got = 0;
        for (int b = 0; b < BATCH; ++b) {
            const long long vi = is64 ? i64[b] : (long long)i32[b];
            const int eb = (int)(((vi % NEXP) + NEXP) % NEXP);
            if (eb == e) {
                if (cnt >= base && got < SPB) s_samp[got++] = b;
                cnt++;
            }
        }
        for (int s2 = got; s2 < SPB; ++s2) s_samp[s2] = -1;
        s_nv = got;
    }
    __syncthreads();
    const int nv = s_nv;
    if (nv == 0) return;            // uniform exit; no further barriers run

    const int krow0 = blockIdx.y * KCH;

    // Stage x chunk (4 KB): gather from L2-resident x (256 KiB total).
    for (int i = tid; i < KCH * SPB; i += 256) {
        const int d = i >> 3, s = i & 7;
        const int sm = s_samp[s];
        xs[d][s] = (sm >= 0) ? x[(size_t)sm * DIM + krow0 + d] : 0.f;
    }
    __syncthreads();

    const int col0 = blockIdx.x * COLS_PER_BLOCK + tid * 4;
    const float4* Wp = (const float4*)(W + (size_t)e * DIM * DIM
                                         + (size_t)krow0 * DIM + col0);

    float4 acc[SPB];
#pragma unroll
    for (int s = 0; s < SPB; ++s) acc[s] = make_float4(0.f, 0.f, 0.f, 0.f);

    // Wave-uniform specialization: avg count per expert is 2 of 16.
    if (nv <= 2)      inner_loop<2>(Wp, xs, acc);
    else if (nv <= 4) inner_loop<4>(Wp, xs, acc);
    else              inner_loop<8>(Wp, xs, acc);

#pragma unroll
    for (int s = 0; s < SPB; ++s) {
        const int sm = s_samp[s];
        if (sm >= 0) {
            float* o = out + (size_t)sm * DIM + col0;
            atomicAdd(o + 0, acc[s].x);
            atomicAdd(o + 1, acc[s].y);
            atomicAdd(o + 2, acc[s].z);
            atomicAdd(o + 3, acc[s].w);
        }
    }
}

extern "C" void kernel_launch(void* const* d_in, const int* in_sizes, int n_in,
                              void* d_out, int out_size, void* d_ws, size_t ws_size,
                              hipStream_t stream) {
    const float* x   = (const float*)d_in[0];
    const void*  idx = d_in[1];
    const float* W   = (const float*)d_in[2];
    float* out = (float*)d_out;

    // d_out is poisoned 0xAA before every timed launch; atomics need zeros.
    hipMemsetAsync(d_out, 0, (size_t)out_size * sizeof(float), stream);

    dim3 grid(COL_TILES, K_CHUNKS, NEXP * 2);
    gmm_kernel<<<grid, 256, 0, stream>>>(x, idx, W, out);
}